// Round 7
// baseline (21.705 us; speedup 1.0000x reference)
//
#include <hip/hip_runtime.h>

// MLPKANLayer: per-(in,out) scalar MLP 1->2->2->1 (relu), summed over in.
// x:[8192,64] f32 -> out:[8192,64] f32.
// Inputs: x, w1[i][o][2], b1[i][o][2], w2[i][o][2][2], b2[i][o][2],
//         w3[i][o][2], b3[i][o]
//
// R6 = the R1 structure (which PASSED post-timing replay validation at
// 18.0 us) with exactly two changes targeting the spill theory:
//   (1) __launch_bounds__(512,4) -> (512,2): VGPR cap 128 -> 256. R1 held
//       104 weight VGPRs + full 16-row unrolled temps under a 128 cap ->
//       scratch spills re-read in the row loop = the 18 us.
//   (2) row loop unroll full -> 4: caps hoisted LDS-load live ranges so
//       real usage ~150-170 VGPR, honestly under the cap, zero scratch.
// Structure: block = 512 threads (8 waves), lane = o. Each wave owns an
// i-chunk of 8 (weights register-resident, loaded once), processes BT=16
// rows; partials combined once via one-shot padded LDS (stride 9, no reuse,
// single barrier pair -- the replay-stable pattern). Grid = 512 blocks.
// R3's 16-wave phased-ps variant diverged on post-timing replay (flaky
// container not ruled out) -- avoided here by construction.

#define IN_SIZE  64
#define OUT_SIZE 64
#define BATCH    8192

constexpr int I_CHUNK = 8;                 // i's per wave
constexpr int WAVES   = 8;                 // waves per block (I_CHUNK*WAVES = 64)
constexpr int BT      = 16;                // batch rows per block
constexpr int PAD     = 9;                 // ps stride (odd -> conflict-free)

__device__ __forceinline__ void conn(float xv, float2 W1, float2 B1,
                                     float4 W2, float2 B2, float2 W3,
                                     float& s) {
    const float h0 = fmaxf(fmaf(xv, W1.x, B1.x), 0.f);
    const float h1 = fmaxf(fmaf(xv, W1.y, B1.y), 0.f);
    float u0 = fmaf(h1, W2.y, fmaf(h0, W2.x, B2.x));
    float u1 = fmaf(h1, W2.w, fmaf(h0, W2.z, B2.y));
    u0 = fmaxf(u0, 0.f);
    u1 = fmaxf(u1, 0.f);
    s = fmaf(u0, W3.x, s);
    s = fmaf(u1, W3.y, s);
}

__global__ __launch_bounds__(512, 2) void kan_kernel(
    const float* __restrict__ x,
    const float* __restrict__ w1, const float* __restrict__ b1,
    const float* __restrict__ w2, const float* __restrict__ b2,
    const float* __restrict__ w3, const float* __restrict__ b3,
    float* __restrict__ out)
{
    const int tid   = threadIdx.x;
    const int o     = tid & 63;
    const int wv    = tid >> 6;
    const int brow0 = blockIdx.x * BT;

    __shared__ float xs[BT * IN_SIZE];             // 4 KiB
    __shared__ float ps[BT * OUT_SIZE * PAD];      // 36 KiB, one-shot

    // Stage x tile: 1024 floats, 512 threads -> one float2 each. Coalesced.
    {
        const float2* xg = reinterpret_cast<const float2*>(x + brow0 * IN_SIZE);
        reinterpret_cast<float2*>(xs)[tid] = xg[tid];
    }

    // Preload this wave's i-chunk weights into registers (coalesced per lane=o).
    const int i0 = wv * I_CHUNK;
    float2 W1[I_CHUNK], B1[I_CHUNK], B2[I_CHUNK], W3[I_CHUNK];
    float4 W2[I_CHUNK];
    float bacc = 0.f;   // this wave's share of sum_i b3[i][o]
    #pragma unroll
    for (int ic = 0; ic < I_CHUNK; ++ic) {
        const int base = (i0 + ic) * OUT_SIZE + o;
        W1[ic] = reinterpret_cast<const float2*>(w1)[base];
        B1[ic] = reinterpret_cast<const float2*>(b1)[base];
        W2[ic] = reinterpret_cast<const float4*>(w2)[base];
        B2[ic] = reinterpret_cast<const float2*>(b2)[base];
        W3[ic] = reinterpret_cast<const float2*>(w3)[base];
        bacc  += b3[base];
    }

    __syncthreads();  // xs ready

    #pragma unroll 4
    for (int r = 0; r < BT; ++r) {
        // 8 wave-uniform x values for this row's i-chunk (LDS broadcast).
        const float4 xa = *reinterpret_cast<const float4*>(xs + r * IN_SIZE + i0);
        const float4 xb = *reinterpret_cast<const float4*>(xs + r * IN_SIZE + i0 + 4);
        float s = bacc;
        conn(xa.x, W1[0], B1[0], W2[0], B2[0], W3[0], s);
        conn(xa.y, W1[1], B1[1], W2[1], B2[1], W3[1], s);
        conn(xa.z, W1[2], B1[2], W2[2], B2[2], W3[2], s);
        conn(xa.w, W1[3], B1[3], W2[3], B2[3], W3[3], s);
        conn(xb.x, W1[4], B1[4], W2[4], B2[4], W3[4], s);
        conn(xb.y, W1[5], B1[5], W2[5], B2[5], W3[5], s);
        conn(xb.z, W1[6], B1[6], W2[6], B2[6], W3[6], s);
        conn(xb.w, W1[7], B1[7], W2[7], B2[7], W3[7], s);
        ps[(r * OUT_SIZE + o) * PAD + wv] = s;
    }

    __syncthreads();

    // Reduce 8 wave-partials per (r,o). 1024 outputs, 512 threads -> 2 each.
    #pragma unroll
    for (int t = tid; t < BT * OUT_SIZE; t += 512) {
        const float* p = ps + t * PAD;
        const float v = ((p[0] + p[1]) + (p[2] + p[3]))
                      + ((p[4] + p[5]) + (p[6] + p[7]));
        out[brow0 * OUT_SIZE + t] = v;   // t = r*64+o, rows contiguous
    }
}

extern "C" void kernel_launch(void* const* d_in, const int* in_sizes, int n_in,
                              void* d_out, int out_size, void* d_ws, size_t ws_size,
                              hipStream_t stream) {
    const float* x  = (const float*)d_in[0];
    const float* w1 = (const float*)d_in[1];
    const float* b1 = (const float*)d_in[2];
    const float* w2 = (const float*)d_in[3];
    const float* b2 = (const float*)d_in[4];
    const float* w3 = (const float*)d_in[5];
    const float* b3 = (const float*)d_in[6];
    float* out = (float*)d_out;

    const int grid = BATCH / BT;   // 512 blocks x 512 threads
    kan_kernel<<<grid, 512, 0, stream>>>(x, w1, b1, w2, b2, w3, b3, out);
}

// Round 8
// 17.110 us; speedup vs baseline: 1.2686x; 1.2686x over previous
//
#include <hip/hip_runtime.h>

// MLPKANLayer: per-(in,out) scalar MLP 1->2->2->1 (relu), summed over in.
// x:[8192,64] f32 -> out:[8192,64] f32.
// Inputs: x, w1[i][o][2], b1[i][o][2], w2[i][o][2][2], b2[i][o][2],
//         w3[i][o][2], b3[i][o]
//
// R7: attack the MEASURED failure mode. R6's profile showed VGPR_Count=112
// with I_CHUNK=8 (104 weight regs): the compiler SINKS the weight loads into
// the row loop (re-reading L2 every row) instead of keeping them resident --
// its occupancy heuristic clamps to the 128-reg boundary. Fix:
//   (1) I_CHUNK=4 -> 52 weight regs + temps ~ 110: fits UNDER 128, so
//       residency costs no occupancy. 16 waves (1024 thr) cover i=64.
//   (2) pin(): empty asm "+v" on every preloaded weight float -- blocks the
//       load-sinking/rematerialization outright. Zero runtime cost.
//   (3) BT=32, grid=256 = 1 block/CU: weight L2 traffic at the 54 MB
//       minimum (one pass per CU), ~1.6 us burst overlapped with compute.
// Cross-wave reduce: phased over RG=8 rows (write ps -> barrier -> 512
// threads reduce 16 contiguous partials -> barrier). Same audited pattern as
// R3; its single post-timing divergence was on a container that also hung
// twice (infra suspect). If it diverges again on a fresh container, the
// pattern is guilty -> switch to ws-based two-kernel partials.

#define IN_SIZE  64
#define OUT_SIZE 64
#define BATCH    8192

constexpr int WAVES   = 16;   // waves per block
constexpr int I_CHUNK = 4;    // i's per wave (WAVES * I_CHUNK = 64)
constexpr int BT      = 32;   // batch rows per block (grid = 256 = 1 block/CU)
constexpr int RG      = 8;    // rows per reduce phase
constexpr int PAD     = 17;   // ps row stride in floats (16 partials + 1 pad)

__device__ __forceinline__ void pin(float& v) {
    asm volatile("" : "+v"(v));   // forces v into a live VGPR; blocks load-sinking
}

__device__ __forceinline__ void conn(float xv, float2 W1, float2 B1,
                                     float4 W2, float2 B2, float2 W3,
                                     float& s) {
    const float h0 = fmaxf(fmaf(xv, W1.x, B1.x), 0.f);
    const float h1 = fmaxf(fmaf(xv, W1.y, B1.y), 0.f);
    float u0 = fmaf(h1, W2.y, fmaf(h0, W2.x, B2.x));
    float u1 = fmaf(h1, W2.w, fmaf(h0, W2.z, B2.y));
    u0 = fmaxf(u0, 0.f);
    u1 = fmaxf(u1, 0.f);
    s = fmaf(u0, W3.x, s);
    s = fmaf(u1, W3.y, s);
}

__global__ __launch_bounds__(1024, 4) void kan_kernel(
    const float* __restrict__ x,
    const float* __restrict__ w1, const float* __restrict__ b1,
    const float* __restrict__ w2, const float* __restrict__ b2,
    const float* __restrict__ w3, const float* __restrict__ b3,
    float* __restrict__ out)
{
    const int tid   = threadIdx.x;
    const int o     = tid & 63;
    const int wv    = tid >> 6;
    const int brow0 = blockIdx.x * BT;

    __shared__ float xs[BT * IN_SIZE];            // 8 KiB
    __shared__ float ps[RG * OUT_SIZE * PAD];     // 8*64*17*4 = 34 KiB

    // Stage x tile: 2048 floats, 1024 threads -> one float2 each. Coalesced.
    {
        const float2* xg = reinterpret_cast<const float2*>(x + brow0 * IN_SIZE);
        reinterpret_cast<float2*>(xs)[tid] = xg[tid];
    }

    // Preload this wave's i-chunk weights into registers (coalesced per lane=o),
    // then PIN them so the compiler cannot sink the loads into the row loop.
    const int i0 = wv * I_CHUNK;
    float2 W1[I_CHUNK], B1[I_CHUNK], B2[I_CHUNK], W3[I_CHUNK];
    float4 W2[I_CHUNK];
    float bacc = 0.f;   // this wave's share of sum_i b3[i][o]
    #pragma unroll
    for (int ic = 0; ic < I_CHUNK; ++ic) {
        const int base = (i0 + ic) * OUT_SIZE + o;
        W1[ic] = reinterpret_cast<const float2*>(w1)[base];
        B1[ic] = reinterpret_cast<const float2*>(b1)[base];
        W2[ic] = reinterpret_cast<const float4*>(w2)[base];
        B2[ic] = reinterpret_cast<const float2*>(b2)[base];
        W3[ic] = reinterpret_cast<const float2*>(w3)[base];
        bacc  += b3[base];
    }
    #pragma unroll
    for (int ic = 0; ic < I_CHUNK; ++ic) {
        pin(W1[ic].x); pin(W1[ic].y);  pin(B1[ic].x); pin(B1[ic].y);
        pin(W2[ic].x); pin(W2[ic].y);  pin(W2[ic].z); pin(W2[ic].w);
        pin(B2[ic].x); pin(B2[ic].y);  pin(W3[ic].x); pin(W3[ic].y);
    }

    __syncthreads();  // xs ready

    #pragma unroll
    for (int g = 0; g < BT / RG; ++g) {
        #pragma unroll
        for (int rr = 0; rr < RG; ++rr) {
            const int r = g * RG + rr;
            // 4 wave-uniform x values for this row's i-chunk (LDS broadcast).
            const float4 xa = *reinterpret_cast<const float4*>(xs + r * IN_SIZE + i0);
            float s = bacc;
            conn(xa.x, W1[0], B1[0], W2[0], B2[0], W3[0], s);
            conn(xa.y, W1[1], B1[1], W2[1], B2[1], W3[1], s);
            conn(xa.z, W1[2], B1[2], W2[2], B2[2], W3[2], s);
            conn(xa.w, W1[3], B1[3], W2[3], B2[3], W3[3], s);
            ps[(rr * OUT_SIZE + o) * PAD + wv] = s;
        }
        __syncthreads();   // ps ready for this 8-row group

        // Reduce 16 wave-partials per (rr,o): 512 outputs, threads 0..511.
        // The 16 partials are contiguous -> compiler can use 4x ds_read_b128.
        if (tid < RG * OUT_SIZE) {
            const float* p = ps + tid * PAD;
            const float v = (((p[0]  + p[1])  + (p[2]  + p[3]))
                          +  ((p[4]  + p[5])  + (p[6]  + p[7])))
                          + (((p[8]  + p[9])  + (p[10] + p[11]))
                          +  ((p[12] + p[13]) + (p[14] + p[15])));
            out[(brow0 + g * RG) * OUT_SIZE + tid] = v;  // tid = rr*64+o
        }
        __syncthreads();   // ps reusable for next phase
    }
}

extern "C" void kernel_launch(void* const* d_in, const int* in_sizes, int n_in,
                              void* d_out, int out_size, void* d_ws, size_t ws_size,
                              hipStream_t stream) {
    const float* x  = (const float*)d_in[0];
    const float* w1 = (const float*)d_in[1];
    const float* b1 = (const float*)d_in[2];
    const float* w2 = (const float*)d_in[3];
    const float* b2 = (const float*)d_in[4];
    const float* w3 = (const float*)d_in[5];
    const float* b3 = (const float*)d_in[6];
    float* out = (float*)d_out;

    const int grid = BATCH / BT;   // 256 blocks x 1024 threads = 1 block/CU
    kan_kernel<<<grid, 1024, 0, stream>>>(x, w1, b1, w2, b2, w3, b3, out);
}